// Round 1
// baseline (669.592 us; speedup 1.0000x reference)
//
#include <hip/hip_runtime.h>
#include <hip/hip_bf16.h>

#define NF 64        // node/edge feature dim
#define N_OUT 128    // output dim
#define CAT 192      // concat dim = 3*64

// ---------------- degree histogram ----------------
__global__ __launch_bounds__(256) void deg_kernel(const int* __restrict__ dst,
                                                  int* __restrict__ deg, int n_edges) {
  int i = blockIdx.x * blockDim.x + threadIdx.x;
  int stride = gridDim.x * blockDim.x;
  for (; i < n_edges; i += stride) atomicAdd(&deg[dst[i]], 1);
}

// ---------------- single-block exclusive scan + norm ----------------
__global__ __launch_bounds__(1024) void scan_kernel(const int* __restrict__ deg,
                                                    int* __restrict__ offs,
                                                    float* __restrict__ norm, int n) {
  __shared__ int wsum[17];
  __shared__ int chunk_base;
  int tid = threadIdx.x;
  int lane = tid & 63, wid = tid >> 6;
  if (tid == 0) chunk_base = 0;
  __syncthreads();
  for (int base = 0; base < n; base += 1024) {
    int i = base + tid;
    int v = (i < n) ? deg[i] : 0;
    int s = v;
    #pragma unroll
    for (int off = 1; off < 64; off <<= 1) {
      int t = __shfl_up(s, off, 64);
      if (lane >= off) s += t;
    }
    if (lane == 63) wsum[wid] = s;
    __syncthreads();
    if (tid == 0) {
      int run = 0;
      #pragma unroll
      for (int w = 0; w < 16; ++w) { int t = wsum[w]; wsum[w] = run; run += t; }
      wsum[16] = run;
    }
    __syncthreads();
    if (i < n) {
      offs[i] = chunk_base + wsum[wid] + s - v;  // exclusive
      norm[i] = rsqrtf(fmaxf((float)v, 1.0f));
    }
    __syncthreads();
    if (tid == 0) chunk_base += wsum[16];
    __syncthreads();
  }
  if (tid == 0) offs[n] = chunk_base;
}

// ---------------- CSR bucket fill ----------------
__global__ __launch_bounds__(256) void fill_kernel(const int* __restrict__ src,
                                                   const int* __restrict__ dst,
                                                   const int* __restrict__ offs,
                                                   int* __restrict__ cursor,
                                                   int2* __restrict__ csr, int n_edges) {
  int i = blockIdx.x * blockDim.x + threadIdx.x;
  int stride = gridDim.x * blockDim.x;
  for (; i < n_edges; i += stride) {
    int d = dst[i];
    int p = atomicAdd(&cursor[d], 1);
    csr[offs[d] + p] = make_int2(i, src[i]);  // (edge id, src node)
  }
}

// ---------------- hop 1: h1[n] = sum of edge_feat rows with dst==n ----------------
__global__ __launch_bounds__(256) void h1_kernel(const float* __restrict__ edge_feat,
                                                 const int2* __restrict__ csr,
                                                 const int* __restrict__ offs,
                                                 float* __restrict__ h1, int n_nodes) {
  int n = blockIdx.x * 4 + (threadIdx.x >> 6);
  if (n >= n_nodes) return;
  int t = threadIdx.x & 63;
  int kb = offs[n], ke = offs[n + 1];
  float a0 = 0.f, a1 = 0.f;
  int k = kb;
  for (; k + 2 <= ke; k += 2) {
    size_t e0 = (size_t)csr[k].x, e1 = (size_t)csr[k + 1].x;
    a0 += edge_feat[e0 * NF + t];
    a1 += edge_feat[e1 * NF + t];
  }
  if (k < ke) a0 += edge_feat[(size_t)csr[k].x * NF + t];
  h1[(size_t)n * NF + t] = a0 + a1;
}

// ---------------- hop 2: h2[n] = sum of h1[src[e]] over incoming edges ----------------
__global__ __launch_bounds__(256) void h2_kernel(const float* __restrict__ h1,
                                                 const int2* __restrict__ csr,
                                                 const int* __restrict__ offs,
                                                 float* __restrict__ h2, int n_nodes) {
  int n = blockIdx.x * 4 + (threadIdx.x >> 6);
  if (n >= n_nodes) return;
  int t = threadIdx.x & 63;
  int kb = offs[n], ke = offs[n + 1];
  float a0 = 0.f, a1 = 0.f;
  int k = kb;
  for (; k + 2 <= ke; k += 2) {
    size_t s0 = (size_t)csr[k].y, s1 = (size_t)csr[k + 1].y;
    a0 += h1[s0 * NF + t];
    a1 += h1[s1 * NF + t];
  }
  if (k < ke) a0 += h1[(size_t)csr[k].y * NF + t];
  h2[(size_t)n * NF + t] = a0 + a1;
}

// ---------------- GEMM: rst = [node_feat, h1*norm, h2*norm] @ W^T + b ----------------
// Wt in LDS as Wt[f*128+o]; 32-node feature tile F[m*196+f].
// Thread (og, ng): outputs o = og*4..og*4+3 for nodes ng*4..ng*4+3.
__global__ __launch_bounds__(256) void gemm_kernel(const float* __restrict__ node_feat,
                                                   const float* __restrict__ h1,
                                                   const float* __restrict__ h2,
                                                   const float* __restrict__ norm,
                                                   const float* __restrict__ W,
                                                   const float* __restrict__ bias,
                                                   float* __restrict__ rst, int n_nodes) {
  __shared__ float Wt[CAT * N_OUT];   // 98304 B
  __shared__ float F[32 * 196];       // 25088 B
  int tid = threadIdx.x;
  for (int idx = tid; idx < CAT * N_OUT; idx += 256) {
    int f = idx >> 7, o = idx & 127;
    Wt[idx] = W[o * CAT + f];
  }
  int og = tid & 31;   // output quad
  int ng = tid >> 5;   // node quad
  float4 b4 = *(const float4*)&bias[og * 4];
  int tiles = (n_nodes + 31) / 32;
  __syncthreads();
  for (int tile = blockIdx.x; tile < tiles; tile += gridDim.x) {
    int nbase = tile * 32;
    __syncthreads();
    for (int idx = tid; idx < 32 * CAT; idx += 256) {
      int m = idx / CAT, f = idx - m * CAT;
      int n = nbase + m;
      float v = 0.f;
      if (n < n_nodes) {
        if (f < 64)       v = node_feat[(size_t)n * NF + f];
        else if (f < 128) v = h1[(size_t)n * NF + (f - 64)] * norm[n];
        else              v = h2[(size_t)n * NF + (f - 128)] * norm[n];
      }
      F[m * 196 + f] = v;
    }
    __syncthreads();
    float acc[4][4] = {{0.f}};
    const float4* Wt4 = (const float4*)Wt;
    for (int f = 0; f < CAT; f += 4) {
      float4 w0 = Wt4[(f + 0) * 32 + og];
      float4 w1 = Wt4[(f + 1) * 32 + og];
      float4 w2 = Wt4[(f + 2) * 32 + og];
      float4 w3 = Wt4[(f + 3) * 32 + og];
      #pragma unroll
      for (int jm = 0; jm < 4; ++jm) {
        const float4 fv = *(const float4*)&F[(ng * 4 + jm) * 196 + f];
        acc[jm][0] += fv.x * w0.x + fv.y * w1.x + fv.z * w2.x + fv.w * w3.x;
        acc[jm][1] += fv.x * w0.y + fv.y * w1.y + fv.z * w2.y + fv.w * w3.y;
        acc[jm][2] += fv.x * w0.z + fv.y * w1.z + fv.z * w2.z + fv.w * w3.z;
        acc[jm][3] += fv.x * w0.w + fv.y * w1.w + fv.z * w2.w + fv.w * w3.w;
      }
    }
    #pragma unroll
    for (int jm = 0; jm < 4; ++jm) {
      int n = nbase + ng * 4 + jm;
      if (n < n_nodes) {
        float4 outv;
        outv.x = acc[jm][0] + b4.x;
        outv.y = acc[jm][1] + b4.y;
        outv.z = acc[jm][2] + b4.z;
        outv.w = acc[jm][3] + b4.w;
        *(float4*)&rst[(size_t)n * N_OUT + og * 4] = outv;
      }
    }
  }
}

// ---------------- est = rst[src] (float4 gather-copy) ----------------
__global__ __launch_bounds__(256) void est_kernel(const float* __restrict__ rst,
                                                  const int* __restrict__ src,
                                                  float* __restrict__ est, int n_edges) {
  const float4* r4 = (const float4*)rst;
  float4* e4 = (float4*)est;
  int total = n_edges * 32;  // 128 floats = 32 float4 per edge
  int i = blockIdx.x * blockDim.x + threadIdx.x;
  int stride = gridDim.x * blockDim.x;
  for (; i < total; i += stride) {
    int e = i >> 5, c = i & 31;
    e4[i] = r4[(size_t)src[e] * 32 + c];
  }
}

extern "C" void kernel_launch(void* const* d_in, const int* in_sizes, int n_in,
                              void* d_out, int out_size, void* d_ws, size_t ws_size,
                              hipStream_t stream) {
  const float* node_feat = (const float*)d_in[0];
  const float* edge_feat = (const float*)d_in[1];
  const float* W = (const float*)d_in[2];
  const float* bias = (const float*)d_in[3];
  const int* src = (const int*)d_in[4];
  const int* dst = (const int*)d_in[5];
  int n_nodes = in_sizes[0] / NF;
  int n_edges = in_sizes[4];

  size_t off = 0;
  auto take = [&](size_t bytes) -> void* {
    void* p = (char*)d_ws + off;
    off += (bytes + 255) & ~(size_t)255;
    return p;
  };
  int* deg = (int*)take((size_t)n_nodes * 4);
  int* cursor = (int*)take((size_t)n_nodes * 4);
  int* offs = (int*)take(((size_t)n_nodes + 1) * 4);
  float* norm = (float*)take((size_t)n_nodes * 4);
  int2* csr = (int2*)take((size_t)n_edges * 8);
  float* h1 = (float*)take((size_t)n_nodes * NF * 4);
  float* h2 = (float*)take((size_t)n_nodes * NF * 4);

  float* rst = (float*)d_out;
  float* est = rst + (size_t)n_nodes * N_OUT;

  hipMemsetAsync(deg, 0, (size_t)n_nodes * 4, stream);
  hipMemsetAsync(cursor, 0, (size_t)n_nodes * 4, stream);

  deg_kernel<<<2048, 256, 0, stream>>>(dst, deg, n_edges);
  scan_kernel<<<1, 1024, 0, stream>>>(deg, offs, norm, n_nodes);
  fill_kernel<<<2048, 256, 0, stream>>>(src, dst, offs, cursor, csr, n_edges);
  int nb = (n_nodes + 3) / 4;
  h1_kernel<<<nb, 256, 0, stream>>>(edge_feat, csr, offs, h1, n_nodes);
  h2_kernel<<<nb, 256, 0, stream>>>(h1, csr, offs, h2, n_nodes);
  int tiles = (n_nodes + 31) / 32;
  gemm_kernel<<<tiles, 256, 0, stream>>>(node_feat, h1, h2, norm, W, bias, rst, n_nodes);
  est_kernel<<<4096, 256, 0, stream>>>(rst, src, est, n_edges);
}

// Round 2
// 492.237 us; speedup vs baseline: 1.3603x; 1.3603x over previous
//
#include <hip/hip_runtime.h>
#include <hip/hip_bf16.h>

#define NF 64        // node/edge feature dim
#define N_OUT 128    // output dim
#define CAT 192      // concat dim = 3*64

// ---------------- degree histogram ----------------
__global__ __launch_bounds__(256) void deg_kernel(const int* __restrict__ dst,
                                                  int* __restrict__ deg, int n_edges) {
  int i = blockIdx.x * blockDim.x + threadIdx.x;
  int stride = gridDim.x * blockDim.x;
  for (; i < n_edges; i += stride) atomicAdd(&deg[dst[i]], 1);
}

// ---------------- parallel scan: A (per-block scan), B (scan block sums), C (add base) ----
// Requires gridA <= 256 blocks of 256 (n <= 65536).
__global__ __launch_bounds__(256) void scanA_kernel(const int* __restrict__ deg,
                                                    int* __restrict__ offs,
                                                    float* __restrict__ norm,
                                                    int* __restrict__ bsum, int n) {
  int tid = threadIdx.x;
  int i = blockIdx.x * 256 + tid;
  int lane = tid & 63, wid = tid >> 6;
  int v = (i < n) ? deg[i] : 0;
  int s = v;
  #pragma unroll
  for (int o = 1; o < 64; o <<= 1) {
    int t = __shfl_up(s, o, 64);
    if (lane >= o) s += t;
  }
  __shared__ int ws[4], wb[4];
  if (lane == 63) ws[wid] = s;
  __syncthreads();
  if (tid == 0) {
    int run = 0;
    #pragma unroll
    for (int w = 0; w < 4; ++w) { wb[w] = run; run += ws[w]; }
    bsum[blockIdx.x] = run;
  }
  __syncthreads();
  if (i < n) {
    offs[i] = wb[wid] + s - v;  // exclusive within block
    norm[i] = rsqrtf(fmaxf((float)v, 1.0f));
  }
}

__global__ __launch_bounds__(256) void scanB_kernel(int* __restrict__ bsum,
                                                    int* __restrict__ offs, int nb, int n) {
  int tid = threadIdx.x, lane = tid & 63, wid = tid >> 6;
  int v = (tid < nb) ? bsum[tid] : 0;
  int s = v;
  #pragma unroll
  for (int o = 1; o < 64; o <<= 1) {
    int t = __shfl_up(s, o, 64);
    if (lane >= o) s += t;
  }
  __shared__ int ws[4], wb[4];
  if (lane == 63) ws[wid] = s;
  __syncthreads();
  if (tid == 0) {
    int run = 0;
    #pragma unroll
    for (int w = 0; w < 4; ++w) { wb[w] = run; run += ws[w]; }
    offs[n] = run;  // grand total
  }
  __syncthreads();
  if (tid < nb) bsum[tid] = wb[wid] + s - v;  // exclusive block base
}

__global__ __launch_bounds__(256) void scanC_kernel(int* __restrict__ offs,
                                                    const int* __restrict__ bsum, int n) {
  int i = blockIdx.x * 256 + threadIdx.x;
  if (i < n) offs[i] += bsum[blockIdx.x];
}

// ---------------- CSR bucket fill ----------------
__global__ __launch_bounds__(256) void fill_kernel(const int* __restrict__ src,
                                                   const int* __restrict__ dst,
                                                   const int* __restrict__ offs,
                                                   int* __restrict__ cursor,
                                                   int2* __restrict__ csr, int n_edges) {
  int i = blockIdx.x * blockDim.x + threadIdx.x;
  int stride = gridDim.x * blockDim.x;
  for (; i < n_edges; i += stride) {
    int d = dst[i];
    int p = atomicAdd(&cursor[d], 1);
    csr[offs[d] + p] = make_int2(i, src[i]);  // (edge id, src node)
  }
}

// ---------------- hop 1: h1[n] = sum of edge_feat rows with dst==n ----------------
__global__ __launch_bounds__(256) void h1_kernel(const float* __restrict__ edge_feat,
                                                 const int2* __restrict__ csr,
                                                 const int* __restrict__ offs,
                                                 float* __restrict__ h1, int n_nodes) {
  int n = blockIdx.x * 4 + (threadIdx.x >> 6);
  if (n >= n_nodes) return;
  int t = threadIdx.x & 63;
  int kb = offs[n], ke = offs[n + 1];
  float a0 = 0.f, a1 = 0.f, a2 = 0.f, a3 = 0.f;
  int k = kb;
  for (; k + 4 <= ke; k += 4) {
    size_t e0 = (size_t)csr[k].x, e1 = (size_t)csr[k + 1].x;
    size_t e2 = (size_t)csr[k + 2].x, e3 = (size_t)csr[k + 3].x;
    a0 += edge_feat[e0 * NF + t];
    a1 += edge_feat[e1 * NF + t];
    a2 += edge_feat[e2 * NF + t];
    a3 += edge_feat[e3 * NF + t];
  }
  for (; k < ke; ++k) a0 += edge_feat[(size_t)csr[k].x * NF + t];
  h1[(size_t)n * NF + t] = (a0 + a1) + (a2 + a3);
}

// ---------------- hop 2: h2[n] = sum of h1[src[e]] over incoming edges ----------------
__global__ __launch_bounds__(256) void h2_kernel(const float* __restrict__ h1,
                                                 const int2* __restrict__ csr,
                                                 const int* __restrict__ offs,
                                                 float* __restrict__ h2, int n_nodes) {
  int n = blockIdx.x * 4 + (threadIdx.x >> 6);
  if (n >= n_nodes) return;
  int t = threadIdx.x & 63;
  int kb = offs[n], ke = offs[n + 1];
  float a0 = 0.f, a1 = 0.f, a2 = 0.f, a3 = 0.f;
  int k = kb;
  for (; k + 4 <= ke; k += 4) {
    size_t s0 = (size_t)csr[k].y, s1 = (size_t)csr[k + 1].y;
    size_t s2 = (size_t)csr[k + 2].y, s3 = (size_t)csr[k + 3].y;
    a0 += h1[s0 * NF + t];
    a1 += h1[s1 * NF + t];
    a2 += h1[s2 * NF + t];
    a3 += h1[s3 * NF + t];
  }
  for (; k < ke; ++k) a0 += h1[(size_t)csr[k].y * NF + t];
  h2[(size_t)n * NF + t] = (a0 + a1) + (a2 + a3);
}

// ---------------- GEMM: rst = [node_feat, h1*norm, h2*norm] @ W^T + b ----------------
// Persistent: 256 blocks x 512 threads (8 waves/CU), 64-node tiles.
// LDS: Wt 98304 B (loaded once per block) + F 49152 B = 147456 B.
__global__ __launch_bounds__(512) void gemm_kernel(const float* __restrict__ node_feat,
                                                   const float* __restrict__ h1,
                                                   const float* __restrict__ h2,
                                                   const float* __restrict__ norm,
                                                   const float* __restrict__ W,
                                                   const float* __restrict__ bias,
                                                   float* __restrict__ rst, int n_nodes) {
  __shared__ float Wt[CAT * N_OUT];   // Wt[f*128+o]
  __shared__ float F[64 * CAT];       // F[m*192+f]
  int tid = threadIdx.x;
  for (int idx = tid; idx < CAT * N_OUT; idx += 512) {
    int f = idx >> 7, o = idx & 127;
    Wt[idx] = W[o * CAT + f];
  }
  int og = tid & 31;   // output quad: o = og*4..og*4+3
  int ng = tid >> 5;   // node quad: nodes ng*4..ng*4+3 (ng in [0,16))
  float4 b4 = *(const float4*)&bias[og * 4];
  const float4* nf4 = (const float4*)node_feat;
  const float4* h1_4 = (const float4*)h1;
  const float4* h2_4 = (const float4*)h2;
  int tiles = (n_nodes + 63) / 64;
  for (int tile = blockIdx.x; tile < tiles; tile += gridDim.x) {
    int nbase = tile * 64;
    __syncthreads();   // previous compute done before overwriting F
    for (int idx = tid; idx < 64 * 48; idx += 512) {
      int m = idx / 48, q = idx - m * 48;   // q: float4 index in [0,48)
      int n = nbase + m;
      float4 v = make_float4(0.f, 0.f, 0.f, 0.f);
      if (n < n_nodes) {
        if (q < 16) {
          v = nf4[(size_t)n * 16 + q];
        } else if (q < 32) {
          float nm = norm[n];
          v = h1_4[(size_t)n * 16 + (q - 16)];
          v.x *= nm; v.y *= nm; v.z *= nm; v.w *= nm;
        } else {
          float nm = norm[n];
          v = h2_4[(size_t)n * 16 + (q - 32)];
          v.x *= nm; v.y *= nm; v.z *= nm; v.w *= nm;
        }
      }
      *(float4*)&F[m * CAT + q * 4] = v;
    }
    __syncthreads();
    float acc[4][4] = {{0.f}};
    const float4* Wt4 = (const float4*)Wt;
    for (int f = 0; f < CAT; f += 4) {
      float4 w0 = Wt4[(f + 0) * 32 + og];
      float4 w1 = Wt4[(f + 1) * 32 + og];
      float4 w2 = Wt4[(f + 2) * 32 + og];
      float4 w3 = Wt4[(f + 3) * 32 + og];
      #pragma unroll
      for (int jm = 0; jm < 4; ++jm) {
        const float4 fv = *(const float4*)&F[(ng * 4 + jm) * CAT + f];
        acc[jm][0] += fv.x * w0.x + fv.y * w1.x + fv.z * w2.x + fv.w * w3.x;
        acc[jm][1] += fv.x * w0.y + fv.y * w1.y + fv.z * w2.y + fv.w * w3.y;
        acc[jm][2] += fv.x * w0.z + fv.y * w1.z + fv.z * w2.z + fv.w * w3.z;
        acc[jm][3] += fv.x * w0.w + fv.y * w1.w + fv.z * w2.w + fv.w * w3.w;
      }
    }
    #pragma unroll
    for (int jm = 0; jm < 4; ++jm) {
      int n = nbase + ng * 4 + jm;
      if (n < n_nodes) {
        float4 outv;
        outv.x = acc[jm][0] + b4.x;
        outv.y = acc[jm][1] + b4.y;
        outv.z = acc[jm][2] + b4.z;
        outv.w = acc[jm][3] + b4.w;
        *(float4*)&rst[(size_t)n * N_OUT + og * 4] = outv;
      }
    }
  }
}

// ---------------- est = rst[src] (float4 gather-copy) ----------------
__global__ __launch_bounds__(256) void est_kernel(const float* __restrict__ rst,
                                                  const int* __restrict__ src,
                                                  float* __restrict__ est, int n_edges) {
  const float4* r4 = (const float4*)rst;
  float4* e4 = (float4*)est;
  int total = n_edges * 32;  // 128 floats = 32 float4 per edge
  int i = blockIdx.x * blockDim.x + threadIdx.x;
  int stride = gridDim.x * blockDim.x;
  for (; i < total; i += stride) {
    int e = i >> 5, c = i & 31;
    e4[i] = r4[(size_t)src[e] * 32 + c];
  }
}

extern "C" void kernel_launch(void* const* d_in, const int* in_sizes, int n_in,
                              void* d_out, int out_size, void* d_ws, size_t ws_size,
                              hipStream_t stream) {
  const float* node_feat = (const float*)d_in[0];
  const float* edge_feat = (const float*)d_in[1];
  const float* W = (const float*)d_in[2];
  const float* bias = (const float*)d_in[3];
  const int* src = (const int*)d_in[4];
  const int* dst = (const int*)d_in[5];
  int n_nodes = in_sizes[0] / NF;
  int n_edges = in_sizes[4];

  size_t off = 0;
  auto take = [&](size_t bytes) -> void* {
    void* p = (char*)d_ws + off;
    off += (bytes + 255) & ~(size_t)255;
    return p;
  };
  int* deg = (int*)take((size_t)n_nodes * 4);
  int* cursor = (int*)take((size_t)n_nodes * 4);
  int* offs = (int*)take(((size_t)n_nodes + 1) * 4);
  float* norm = (float*)take((size_t)n_nodes * 4);
  int* bsum = (int*)take(256 * 4);
  int2* csr = (int2*)take((size_t)n_edges * 8);
  float* h1 = (float*)take((size_t)n_nodes * NF * 4);
  float* h2 = (float*)take((size_t)n_nodes * NF * 4);

  float* rst = (float*)d_out;
  float* est = rst + (size_t)n_nodes * N_OUT;

  hipMemsetAsync(deg, 0, (size_t)n_nodes * 4, stream);
  hipMemsetAsync(cursor, 0, (size_t)n_nodes * 4, stream);

  deg_kernel<<<2048, 256, 0, stream>>>(dst, deg, n_edges);
  int nbs = (n_nodes + 255) / 256;     // 196 <= 256
  scanA_kernel<<<nbs, 256, 0, stream>>>(deg, offs, norm, bsum, n_nodes);
  scanB_kernel<<<1, 256, 0, stream>>>(bsum, offs, nbs, n_nodes);
  scanC_kernel<<<nbs, 256, 0, stream>>>(offs, bsum, n_nodes);
  fill_kernel<<<2048, 256, 0, stream>>>(src, dst, offs, cursor, csr, n_edges);
  int nb = (n_nodes + 3) / 4;
  h1_kernel<<<nb, 256, 0, stream>>>(edge_feat, csr, offs, h1, n_nodes);
  h2_kernel<<<nb, 256, 0, stream>>>(h1, csr, offs, h2, n_nodes);
  gemm_kernel<<<256, 512, 0, stream>>>(node_feat, h1, h2, norm, W, bias, rst, n_nodes);
  est_kernel<<<4096, 256, 0, stream>>>(rst, src, est, n_edges);
}

// Round 3
// 407.254 us; speedup vs baseline: 1.6442x; 1.2087x over previous
//
#include <hip/hip_runtime.h>
#include <hip/hip_bf16.h>

#define NF 64        // node/edge feature dim
#define N_OUT 128    // output dim
#define CAT 192      // concat dim = 3*64

typedef __attribute__((ext_vector_type(4))) float f32x4;
typedef __attribute__((ext_vector_type(8))) short bf16x8;

__device__ inline short f2bf(float x) {   // round-to-nearest-even bf16
  unsigned u = __float_as_uint(x);
  unsigned r = (u + 0x7fff + ((u >> 16) & 1)) >> 16;
  return (short)r;
}

// ---------------- degree histogram ----------------
__global__ __launch_bounds__(256) void deg_kernel(const int* __restrict__ dst,
                                                  int* __restrict__ deg, int n_edges) {
  int i = blockIdx.x * blockDim.x + threadIdx.x;
  int stride = gridDim.x * blockDim.x;
  for (; i < n_edges; i += stride) atomicAdd(&deg[dst[i]], 1);
}

// ---------------- parallel scan ----------------
__global__ __launch_bounds__(256) void scanA_kernel(const int* __restrict__ deg,
                                                    int* __restrict__ offs,
                                                    float* __restrict__ norm,
                                                    int* __restrict__ bsum, int n) {
  int tid = threadIdx.x;
  int i = blockIdx.x * 256 + tid;
  int lane = tid & 63, wid = tid >> 6;
  int v = (i < n) ? deg[i] : 0;
  int s = v;
  #pragma unroll
  for (int o = 1; o < 64; o <<= 1) {
    int t = __shfl_up(s, o, 64);
    if (lane >= o) s += t;
  }
  __shared__ int ws[4], wb[4];
  if (lane == 63) ws[wid] = s;
  __syncthreads();
  if (tid == 0) {
    int run = 0;
    #pragma unroll
    for (int w = 0; w < 4; ++w) { wb[w] = run; run += ws[w]; }
    bsum[blockIdx.x] = run;
  }
  __syncthreads();
  if (i < n) {
    offs[i] = wb[wid] + s - v;
    norm[i] = rsqrtf(fmaxf((float)v, 1.0f));
  }
}

__global__ __launch_bounds__(256) void scanB_kernel(int* __restrict__ bsum,
                                                    int* __restrict__ offs, int nb, int n) {
  int tid = threadIdx.x, lane = tid & 63, wid = tid >> 6;
  int v = (tid < nb) ? bsum[tid] : 0;
  int s = v;
  #pragma unroll
  for (int o = 1; o < 64; o <<= 1) {
    int t = __shfl_up(s, o, 64);
    if (lane >= o) s += t;
  }
  __shared__ int ws[4], wb[4];
  if (lane == 63) ws[wid] = s;
  __syncthreads();
  if (tid == 0) {
    int run = 0;
    #pragma unroll
    for (int w = 0; w < 4; ++w) { wb[w] = run; run += ws[w]; }
    offs[n] = run;
  }
  __syncthreads();
  if (tid < nb) bsum[tid] = wb[wid] + s - v;
}

__global__ __launch_bounds__(256) void scanC_kernel(int* __restrict__ offs,
                                                    const int* __restrict__ bsum, int n) {
  int i = blockIdx.x * 256 + threadIdx.x;
  if (i < n) offs[i] += bsum[blockIdx.x];
}

// ---------------- CSR bucket fill (split arrays) ----------------
__global__ __launch_bounds__(256) void fill_kernel(const int* __restrict__ src,
                                                   const int* __restrict__ dst,
                                                   const int* __restrict__ offs,
                                                   int* __restrict__ cursor,
                                                   int* __restrict__ csr_e,
                                                   int* __restrict__ csr_s, int n_edges) {
  int i = blockIdx.x * blockDim.x + threadIdx.x;
  int stride = gridDim.x * blockDim.x;
  for (; i < n_edges; i += stride) {
    int d = dst[i];
    int p = atomicAdd(&cursor[d], 1);
    int slot = offs[d] + p;
    csr_e[slot] = i;
    csr_s[slot] = src[i];
  }
}

// ---------------- hop 1 ----------------
__global__ __launch_bounds__(256) void h1_kernel(const float* __restrict__ edge_feat,
                                                 const int* __restrict__ csr_e,
                                                 const int* __restrict__ offs,
                                                 float* __restrict__ h1, int n_nodes) {
  int n = blockIdx.x * 4 + (threadIdx.x >> 6);
  if (n >= n_nodes) return;
  int t = threadIdx.x & 63;
  int kb = offs[n], ke = offs[n + 1];
  float a0 = 0.f, a1 = 0.f, a2 = 0.f, a3 = 0.f;
  float a4 = 0.f, a5 = 0.f, a6 = 0.f, a7 = 0.f;
  int k = kb;
  for (; k + 8 <= ke; k += 8) {
    size_t e0 = (size_t)csr_e[k],     e1 = (size_t)csr_e[k + 1];
    size_t e2 = (size_t)csr_e[k + 2], e3 = (size_t)csr_e[k + 3];
    size_t e4 = (size_t)csr_e[k + 4], e5 = (size_t)csr_e[k + 5];
    size_t e6 = (size_t)csr_e[k + 6], e7 = (size_t)csr_e[k + 7];
    a0 += __builtin_nontemporal_load(&edge_feat[e0 * NF + t]);
    a1 += __builtin_nontemporal_load(&edge_feat[e1 * NF + t]);
    a2 += __builtin_nontemporal_load(&edge_feat[e2 * NF + t]);
    a3 += __builtin_nontemporal_load(&edge_feat[e3 * NF + t]);
    a4 += __builtin_nontemporal_load(&edge_feat[e4 * NF + t]);
    a5 += __builtin_nontemporal_load(&edge_feat[e5 * NF + t]);
    a6 += __builtin_nontemporal_load(&edge_feat[e6 * NF + t]);
    a7 += __builtin_nontemporal_load(&edge_feat[e7 * NF + t]);
  }
  for (; k < ke; ++k)
    a0 += __builtin_nontemporal_load(&edge_feat[(size_t)csr_e[k] * NF + t]);
  h1[(size_t)n * NF + t] = ((a0 + a1) + (a2 + a3)) + ((a4 + a5) + (a6 + a7));
}

// ---------------- hop 2 ----------------
__global__ __launch_bounds__(256) void h2_kernel(const float* __restrict__ h1,
                                                 const int* __restrict__ csr_s,
                                                 const int* __restrict__ offs,
                                                 float* __restrict__ h2, int n_nodes) {
  int n = blockIdx.x * 4 + (threadIdx.x >> 6);
  if (n >= n_nodes) return;
  int t = threadIdx.x & 63;
  int kb = offs[n], ke = offs[n + 1];
  float a0 = 0.f, a1 = 0.f, a2 = 0.f, a3 = 0.f;
  int k = kb;
  for (; k + 4 <= ke; k += 4) {
    size_t s0 = (size_t)csr_s[k],     s1 = (size_t)csr_s[k + 1];
    size_t s2 = (size_t)csr_s[k + 2], s3 = (size_t)csr_s[k + 3];
    a0 += h1[s0 * NF + t];
    a1 += h1[s1 * NF + t];
    a2 += h1[s2 * NF + t];
    a3 += h1[s3 * NF + t];
  }
  for (; k < ke; ++k) a0 += h1[(size_t)csr_s[k] * NF + t];
  h2[(size_t)n * NF + t] = (a0 + a1) + (a2 + a3);
}

// ---------------- GEMM via bf16 MFMA ----------------
// rst[n][o] = sum_f F[n][f] * W[o][f] + b[o], F = [nf, h1*norm, h2*norm], K=192.
// Block: 256 thr = 4 waves. Tile: 32 nodes x 128 outs. Wave w: cols [w*32, w*32+32).
// B (W^T) held in registers: 6 k-steps x 2 col-frags. A staged in LDS (32 x 200 bf16).
__global__ __launch_bounds__(256) void gemm_kernel(const float* __restrict__ node_feat,
                                                   const float* __restrict__ h1,
                                                   const float* __restrict__ h2,
                                                   const float* __restrict__ norm,
                                                   const float* __restrict__ W,
                                                   const float* __restrict__ bias,
                                                   float* __restrict__ rst, int n_nodes) {
  __shared__ short F[32 * 200];   // bf16, row stride 200 elems (400 B) vs 192 used
  int tid = threadIdx.x;
  int l = tid & 63, w = tid >> 6;
  int l15 = l & 15, l4 = l >> 4;

  // stage B fragments (per-wave cols) into registers, bf16
  bf16x8 Bf[6][2];
  #pragma unroll
  for (int c = 0; c < 2; ++c) {
    int col = w * 32 + c * 16 + l15;
    const float* wp = &W[(size_t)col * CAT];
    #pragma unroll
    for (int ks = 0; ks < 6; ++ks) {
      int k0 = ks * 32 + l4 * 8;
      bf16x8 b;
      #pragma unroll
      for (int j = 0; j < 8; ++j) b[j] = f2bf(wp[k0 + j]);
      Bf[ks][c] = b;
    }
  }
  float bias0 = bias[w * 32 + l15];
  float bias1 = bias[w * 32 + 16 + l15];

  int tiles = (n_nodes + 31) / 32;
  for (int tile = blockIdx.x; tile < tiles; tile += gridDim.x) {
    int nbase = tile * 32;
    __syncthreads();   // protect F from previous iteration's readers
    // stage F: 32 rows x 24 groups of 8 floats -> bf16x8
    for (int idx = tid; idx < 768; idx += 256) {
      int m = idx / 24, q = idx - m * 24;
      int n = nbase + m;
      bf16x8 pk;
      if (n < n_nodes) {
        const float* sp;
        float scale = 1.f;
        if (q < 8)       sp = &node_feat[(size_t)n * NF + q * 8];
        else if (q < 16) { sp = &h1[(size_t)n * NF + (q - 8) * 8]; scale = norm[n]; }
        else             { sp = &h2[(size_t)n * NF + (q - 16) * 8]; scale = norm[n]; }
        f32x4 v0 = *(const f32x4*)sp;
        f32x4 v1 = *(const f32x4*)(sp + 4);
        pk[0] = f2bf(v0.x * scale); pk[1] = f2bf(v0.y * scale);
        pk[2] = f2bf(v0.z * scale); pk[3] = f2bf(v0.w * scale);
        pk[4] = f2bf(v1.x * scale); pk[5] = f2bf(v1.y * scale);
        pk[6] = f2bf(v1.z * scale); pk[7] = f2bf(v1.w * scale);
      } else {
        pk = bf16x8{0,0,0,0,0,0,0,0};
      }
      *(bf16x8*)&F[m * 200 + q * 8] = pk;
    }
    __syncthreads();
    f32x4 acc00 = {0.f,0.f,0.f,0.f}, acc01 = {0.f,0.f,0.f,0.f};
    f32x4 acc10 = {0.f,0.f,0.f,0.f}, acc11 = {0.f,0.f,0.f,0.f};
    #pragma unroll
    for (int ks = 0; ks < 6; ++ks) {
      bf16x8 a0 = *(const bf16x8*)&F[l15 * 200 + ks * 32 + l4 * 8];
      bf16x8 a1 = *(const bf16x8*)&F[(16 + l15) * 200 + ks * 32 + l4 * 8];
      acc00 = __builtin_amdgcn_mfma_f32_16x16x32_bf16(a0, Bf[ks][0], acc00, 0, 0, 0);
      acc01 = __builtin_amdgcn_mfma_f32_16x16x32_bf16(a0, Bf[ks][1], acc01, 0, 0, 0);
      acc10 = __builtin_amdgcn_mfma_f32_16x16x32_bf16(a1, Bf[ks][0], acc10, 0, 0, 0);
      acc11 = __builtin_amdgcn_mfma_f32_16x16x32_bf16(a1, Bf[ks][1], acc11, 0, 0, 0);
    }
    // epilogue: D[row=(l>>4)*4+r][col=l15] per 16x16 frag
    #pragma unroll
    for (int rt = 0; rt < 2; ++rt) {
      f32x4 ac0 = rt ? acc10 : acc00;
      f32x4 ac1 = rt ? acc11 : acc01;
      #pragma unroll
      for (int r = 0; r < 4; ++r) {
        int n = nbase + rt * 16 + l4 * 4 + r;
        if (n < n_nodes) {
          int o0 = w * 32 + l15;
          rst[(size_t)n * N_OUT + o0] = ac0[r] + bias0;
          rst[(size_t)n * N_OUT + o0 + 16] = ac1[r] + bias1;
        }
      }
    }
  }
}

// ---------------- est = rst[src] (nontemporal float4 gather-copy) ----------------
__global__ __launch_bounds__(256) void est_kernel(const float* __restrict__ rst,
                                                  const int* __restrict__ src,
                                                  float* __restrict__ est, int n_edges) {
  const f32x4* r4 = (const f32x4*)rst;
  f32x4* e4 = (f32x4*)est;
  int total = n_edges * 32;
  int i = blockIdx.x * blockDim.x + threadIdx.x;
  int stride = gridDim.x * blockDim.x;
  for (; i < total; i += stride) {
    int e = i >> 5, c = i & 31;
    f32x4 v = r4[(size_t)src[e] * 32 + c];
    __builtin_nontemporal_store(v, &e4[i]);
  }
}

extern "C" void kernel_launch(void* const* d_in, const int* in_sizes, int n_in,
                              void* d_out, int out_size, void* d_ws, size_t ws_size,
                              hipStream_t stream) {
  const float* node_feat = (const float*)d_in[0];
  const float* edge_feat = (const float*)d_in[1];
  const float* W = (const float*)d_in[2];
  const float* bias = (const float*)d_in[3];
  const int* src = (const int*)d_in[4];
  const int* dst = (const int*)d_in[5];
  int n_nodes = in_sizes[0] / NF;
  int n_edges = in_sizes[4];

  size_t off = 0;
  auto take = [&](size_t bytes) -> void* {
    void* p = (char*)d_ws + off;
    off += (bytes + 255) & ~(size_t)255;
    return p;
  };
  int* deg = (int*)take((size_t)n_nodes * 4);
  int* cursor = (int*)take((size_t)n_nodes * 4);
  int* offs = (int*)take(((size_t)n_nodes + 1) * 4);
  float* norm = (float*)take((size_t)n_nodes * 4);
  int* bsum = (int*)take(256 * 4);
  int* csr_e = (int*)take((size_t)n_edges * 4);
  int* csr_s = (int*)take((size_t)n_edges * 4);
  float* h1 = (float*)take((size_t)n_nodes * NF * 4);
  float* h2 = (float*)take((size_t)n_nodes * NF * 4);

  float* rst = (float*)d_out;
  float* est = rst + (size_t)n_nodes * N_OUT;

  hipMemsetAsync(deg, 0, (size_t)n_nodes * 4, stream);
  hipMemsetAsync(cursor, 0, (size_t)n_nodes * 4, stream);

  deg_kernel<<<2048, 256, 0, stream>>>(dst, deg, n_edges);
  int nbs = (n_nodes + 255) / 256;
  scanA_kernel<<<nbs, 256, 0, stream>>>(deg, offs, norm, bsum, n_nodes);
  scanB_kernel<<<1, 256, 0, stream>>>(bsum, offs, nbs, n_nodes);
  scanC_kernel<<<nbs, 256, 0, stream>>>(offs, bsum, n_nodes);
  fill_kernel<<<2048, 256, 0, stream>>>(src, dst, offs, cursor, csr_e, csr_s, n_edges);
  int nb = (n_nodes + 3) / 4;
  h1_kernel<<<nb, 256, 0, stream>>>(edge_feat, csr_e, offs, h1, n_nodes);
  h2_kernel<<<nb, 256, 0, stream>>>(h1, csr_s, offs, h2, n_nodes);
  gemm_kernel<<<512, 256, 0, stream>>>(node_feat, h1, h2, norm, W, bias, rst, n_nodes);
  est_kernel<<<4096, 256, 0, stream>>>(rst, src, est, n_edges);
}

// Round 4
// 401.670 us; speedup vs baseline: 1.6670x; 1.0139x over previous
//
#include <hip/hip_runtime.h>
#include <hip/hip_bf16.h>

#define NF 64        // node/edge feature dim
#define N_OUT 128    // output dim
#define CAT 192      // concat dim = 3*64

typedef __attribute__((ext_vector_type(4))) float f32x4;
typedef __attribute__((ext_vector_type(8))) short bf16x8;

__device__ inline short f2bf(float x) {   // round-to-nearest-even bf16
  unsigned u = __float_as_uint(x);
  unsigned r = (u + 0x7fff + ((u >> 16) & 1)) >> 16;
  return (short)r;
}

__device__ inline f32x4 sx4(f32x4 v, int m) {
  f32x4 r;
  r.x = __shfl_xor(v.x, m, 64);
  r.y = __shfl_xor(v.y, m, 64);
  r.z = __shfl_xor(v.z, m, 64);
  r.w = __shfl_xor(v.w, m, 64);
  return r;
}

// ---------------- degree histogram ----------------
__global__ __launch_bounds__(256) void deg_kernel(const int* __restrict__ dst,
                                                  int* __restrict__ deg, int n_edges) {
  int i = blockIdx.x * blockDim.x + threadIdx.x;
  int stride = gridDim.x * blockDim.x;
  for (; i < n_edges; i += stride) {
    int d = __builtin_nontemporal_load(&dst[i]);
    atomicAdd(&deg[d], 1);
  }
}

// ---------------- parallel scan ----------------
__global__ __launch_bounds__(256) void scanA_kernel(const int* __restrict__ deg,
                                                    int* __restrict__ offs,
                                                    float* __restrict__ norm,
                                                    int* __restrict__ bsum, int n) {
  int tid = threadIdx.x;
  int i = blockIdx.x * 256 + tid;
  int lane = tid & 63, wid = tid >> 6;
  int v = (i < n) ? deg[i] : 0;
  int s = v;
  #pragma unroll
  for (int o = 1; o < 64; o <<= 1) {
    int t = __shfl_up(s, o, 64);
    if (lane >= o) s += t;
  }
  __shared__ int ws[4], wb[4];
  if (lane == 63) ws[wid] = s;
  __syncthreads();
  if (tid == 0) {
    int run = 0;
    #pragma unroll
    for (int w = 0; w < 4; ++w) { wb[w] = run; run += ws[w]; }
    bsum[blockIdx.x] = run;
  }
  __syncthreads();
  if (i < n) {
    offs[i] = wb[wid] + s - v;
    norm[i] = rsqrtf(fmaxf((float)v, 1.0f));
  }
}

__global__ __launch_bounds__(256) void scanB_kernel(int* __restrict__ bsum, int nb) {
  int tid = threadIdx.x, lane = tid & 63, wid = tid >> 6;
  int v = (tid < nb) ? bsum[tid] : 0;
  int s = v;
  #pragma unroll
  for (int o = 1; o < 64; o <<= 1) {
    int t = __shfl_up(s, o, 64);
    if (lane >= o) s += t;
  }
  __shared__ int ws[4], wb[4];
  if (lane == 63) ws[wid] = s;
  __syncthreads();
  if (tid == 0) {
    int run = 0;
    #pragma unroll
    for (int w = 0; w < 4; ++w) { wb[w] = run; run += ws[w]; }
  }
  __syncthreads();
  if (tid < nb) bsum[tid] = wb[wid] + s - v;
}

__global__ __launch_bounds__(256) void scanC_kernel(int* __restrict__ offs,
                                                    const int* __restrict__ bsum, int n) {
  int i = blockIdx.x * 256 + threadIdx.x;
  if (i < n) offs[i] += bsum[blockIdx.x];
}

// ---------------- CSR bucket fill: offs doubles as cursor ----------------
// After this kernel, offs[d] = original offs[d+1]; node n's slots are
// [ (n ? offs[n-1] : 0), offs[n] ).
__global__ __launch_bounds__(256) void fill_kernel(const int* __restrict__ src,
                                                   const int* __restrict__ dst,
                                                   int* __restrict__ offs,
                                                   int2* __restrict__ csr, int n_edges) {
  int i = blockIdx.x * blockDim.x + threadIdx.x;
  int stride = gridDim.x * blockDim.x;
  for (; i < n_edges; i += stride) {
    int d = __builtin_nontemporal_load(&dst[i]);
    int s = __builtin_nontemporal_load(&src[i]);
    int p = atomicAdd(&offs[d], 1);
    csr[p] = make_int2(i, s);
  }
}

// ---------------- hop 1: 16 lanes x float4 per row, 4 rows per wave-load ----------------
__global__ __launch_bounds__(256) void h1_kernel(const float* __restrict__ edge_feat,
                                                 const int2* __restrict__ csr,
                                                 const int* __restrict__ offs,
                                                 float* __restrict__ h1, int n_nodes) {
  int n = blockIdx.x * 4 + (threadIdx.x >> 6);
  if (n >= n_nodes) return;
  int l = threadIdx.x & 63;
  int l15 = l & 15, l4 = l >> 4;
  int kb = n ? offs[n - 1] : 0;
  int ke = offs[n];
  f32x4 acc0 = {0.f, 0.f, 0.f, 0.f}, acc1 = {0.f, 0.f, 0.f, 0.f};
  int k = kb;
  for (; k + 8 <= ke; k += 8) {
    int e0 = csr[k + l4].x;
    int e1 = csr[k + 4 + l4].x;
    f32x4 v0 = __builtin_nontemporal_load((const f32x4*)&edge_feat[(size_t)e0 * NF + l15 * 4]);
    f32x4 v1 = __builtin_nontemporal_load((const f32x4*)&edge_feat[(size_t)e1 * NF + l15 * 4]);
    acc0 += v0;
    acc1 += v1;
  }
  if (k + 4 <= ke) {
    int e = csr[k + l4].x;
    acc0 += __builtin_nontemporal_load((const f32x4*)&edge_feat[(size_t)e * NF + l15 * 4]);
    k += 4;
  }
  int rem = ke - k;   // 0..3
  if (l4 < rem) {
    int e = csr[k + l4].x;
    acc1 += __builtin_nontemporal_load((const f32x4*)&edge_feat[(size_t)e * NF + l15 * 4]);
  }
  f32x4 t = acc0 + acc1;
  t += sx4(t, 16);
  t += sx4(t, 32);
  if (l4 == 0) *(f32x4*)&h1[(size_t)n * NF + l15 * 4] = t;
}

// ---------------- hop 2: same structure, rows from h1 (cached) ----------------
__global__ __launch_bounds__(256) void h2_kernel(const float* __restrict__ h1,
                                                 const int2* __restrict__ csr,
                                                 const int* __restrict__ offs,
                                                 float* __restrict__ h2, int n_nodes) {
  int n = blockIdx.x * 4 + (threadIdx.x >> 6);
  if (n >= n_nodes) return;
  int l = threadIdx.x & 63;
  int l15 = l & 15, l4 = l >> 4;
  int kb = n ? offs[n - 1] : 0;
  int ke = offs[n];
  f32x4 acc0 = {0.f, 0.f, 0.f, 0.f}, acc1 = {0.f, 0.f, 0.f, 0.f};
  int k = kb;
  for (; k + 8 <= ke; k += 8) {
    int s0 = csr[k + l4].y;
    int s1 = csr[k + 4 + l4].y;
    acc0 += *(const f32x4*)&h1[(size_t)s0 * NF + l15 * 4];
    acc1 += *(const f32x4*)&h1[(size_t)s1 * NF + l15 * 4];
  }
  if (k + 4 <= ke) {
    int s = csr[k + l4].y;
    acc0 += *(const f32x4*)&h1[(size_t)s * NF + l15 * 4];
    k += 4;
  }
  int rem = ke - k;
  if (l4 < rem) {
    int s = csr[k + l4].y;
    acc1 += *(const f32x4*)&h1[(size_t)s * NF + l15 * 4];
  }
  f32x4 t = acc0 + acc1;
  t += sx4(t, 16);
  t += sx4(t, 32);
  if (l4 == 0) *(f32x4*)&h2[(size_t)n * NF + l15 * 4] = t;
}

// ---------------- GEMM via bf16 MFMA (unchanged from round 3) ----------------
__global__ __launch_bounds__(256) void gemm_kernel(const float* __restrict__ node_feat,
                                                   const float* __restrict__ h1,
                                                   const float* __restrict__ h2,
                                                   const float* __restrict__ norm,
                                                   const float* __restrict__ W,
                                                   const float* __restrict__ bias,
                                                   float* __restrict__ rst, int n_nodes) {
  __shared__ short F[32 * 200];
  int tid = threadIdx.x;
  int l = tid & 63, w = tid >> 6;
  int l15 = l & 15, l4 = l >> 4;

  bf16x8 Bf[6][2];
  #pragma unroll
  for (int c = 0; c < 2; ++c) {
    int col = w * 32 + c * 16 + l15;
    const float* wp = &W[(size_t)col * CAT];
    #pragma unroll
    for (int ks = 0; ks < 6; ++ks) {
      int k0 = ks * 32 + l4 * 8;
      bf16x8 b;
      #pragma unroll
      for (int j = 0; j < 8; ++j) b[j] = f2bf(wp[k0 + j]);
      Bf[ks][c] = b;
    }
  }
  float bias0 = bias[w * 32 + l15];
  float bias1 = bias[w * 32 + 16 + l15];

  int tiles = (n_nodes + 31) / 32;
  for (int tile = blockIdx.x; tile < tiles; tile += gridDim.x) {
    int nbase = tile * 32;
    __syncthreads();
    for (int idx = tid; idx < 768; idx += 256) {
      int m = idx / 24, q = idx - m * 24;
      int n = nbase + m;
      bf16x8 pk;
      if (n < n_nodes) {
        const float* sp;
        float scale = 1.f;
        if (q < 8)       sp = &node_feat[(size_t)n * NF + q * 8];
        else if (q < 16) { sp = &h1[(size_t)n * NF + (q - 8) * 8]; scale = norm[n]; }
        else             { sp = &h2[(size_t)n * NF + (q - 16) * 8]; scale = norm[n]; }
        f32x4 v0 = *(const f32x4*)sp;
        f32x4 v1 = *(const f32x4*)(sp + 4);
        pk[0] = f2bf(v0.x * scale); pk[1] = f2bf(v0.y * scale);
        pk[2] = f2bf(v0.z * scale); pk[3] = f2bf(v0.w * scale);
        pk[4] = f2bf(v1.x * scale); pk[5] = f2bf(v1.y * scale);
        pk[6] = f2bf(v1.z * scale); pk[7] = f2bf(v1.w * scale);
      } else {
        pk = bf16x8{0,0,0,0,0,0,0,0};
      }
      *(bf16x8*)&F[m * 200 + q * 8] = pk;
    }
    __syncthreads();
    f32x4 acc00 = {0.f,0.f,0.f,0.f}, acc01 = {0.f,0.f,0.f,0.f};
    f32x4 acc10 = {0.f,0.f,0.f,0.f}, acc11 = {0.f,0.f,0.f,0.f};
    #pragma unroll
    for (int ks = 0; ks < 6; ++ks) {
      bf16x8 a0 = *(const bf16x8*)&F[l15 * 200 + ks * 32 + l4 * 8];
      bf16x8 a1 = *(const bf16x8*)&F[(16 + l15) * 200 + ks * 32 + l4 * 8];
      acc00 = __builtin_amdgcn_mfma_f32_16x16x32_bf16(a0, Bf[ks][0], acc00, 0, 0, 0);
      acc01 = __builtin_amdgcn_mfma_f32_16x16x32_bf16(a0, Bf[ks][1], acc01, 0, 0, 0);
      acc10 = __builtin_amdgcn_mfma_f32_16x16x32_bf16(a1, Bf[ks][0], acc10, 0, 0, 0);
      acc11 = __builtin_amdgcn_mfma_f32_16x16x32_bf16(a1, Bf[ks][1], acc11, 0, 0, 0);
    }
    #pragma unroll
    for (int rt = 0; rt < 2; ++rt) {
      f32x4 ac0 = rt ? acc10 : acc00;
      f32x4 ac1 = rt ? acc11 : acc01;
      #pragma unroll
      for (int r = 0; r < 4; ++r) {
        int n = nbase + rt * 16 + l4 * 4 + r;
        if (n < n_nodes) {
          int o0 = w * 32 + l15;
          rst[(size_t)n * N_OUT + o0] = ac0[r] + bias0;
          rst[(size_t)n * N_OUT + o0 + 16] = ac1[r] + bias1;
        }
      }
    }
  }
}

// ---------------- est = rst[src] (nontemporal float4 gather-copy) ----------------
__global__ __launch_bounds__(256) void est_kernel(const float* __restrict__ rst,
                                                  const int* __restrict__ src,
                                                  float* __restrict__ est, int n_edges) {
  const f32x4* r4 = (const f32x4*)rst;
  f32x4* e4 = (f32x4*)est;
  int total = n_edges * 32;
  int i = blockIdx.x * blockDim.x + threadIdx.x;
  int stride = gridDim.x * blockDim.x;
  for (; i < total; i += stride) {
    int e = i >> 5, c = i & 31;
    f32x4 v = r4[(size_t)src[e] * 32 + c];
    __builtin_nontemporal_store(v, &e4[i]);
  }
}

extern "C" void kernel_launch(void* const* d_in, const int* in_sizes, int n_in,
                              void* d_out, int out_size, void* d_ws, size_t ws_size,
                              hipStream_t stream) {
  const float* node_feat = (const float*)d_in[0];
  const float* edge_feat = (const float*)d_in[1];
  const float* W = (const float*)d_in[2];
  const float* bias = (const float*)d_in[3];
  const int* src = (const int*)d_in[4];
  const int* dst = (const int*)d_in[5];
  int n_nodes = in_sizes[0] / NF;
  int n_edges = in_sizes[4];

  size_t off = 0;
  auto take = [&](size_t bytes) -> void* {
    void* p = (char*)d_ws + off;
    off += (bytes + 255) & ~(size_t)255;
    return p;
  };
  int* deg = (int*)take((size_t)n_nodes * 4);
  int* offs = (int*)take(((size_t)n_nodes + 1) * 4);
  float* norm = (float*)take((size_t)n_nodes * 4);
  int* bsum = (int*)take(256 * 4);
  int2* csr = (int2*)take((size_t)n_edges * 8);
  float* h1 = (float*)take((size_t)n_nodes * NF * 4);
  float* h2 = (float*)take((size_t)n_nodes * NF * 4);

  float* rst = (float*)d_out;
  float* est = rst + (size_t)n_nodes * N_OUT;

  hipMemsetAsync(deg, 0, (size_t)n_nodes * 4, stream);

  deg_kernel<<<2048, 256, 0, stream>>>(dst, deg, n_edges);
  int nbs = (n_nodes + 255) / 256;
  scanA_kernel<<<nbs, 256, 0, stream>>>(deg, offs, norm, bsum, n_nodes);
  scanB_kernel<<<1, 256, 0, stream>>>(bsum, nbs);
  scanC_kernel<<<nbs, 256, 0, stream>>>(offs, bsum, n_nodes);
  fill_kernel<<<2048, 256, 0, stream>>>(src, dst, offs, csr, n_edges);
  int nb = (n_nodes + 3) / 4;
  h1_kernel<<<nb, 256, 0, stream>>>(edge_feat, csr, offs, h1, n_nodes);
  h2_kernel<<<nb, 256, 0, stream>>>(h1, csr, offs, h2, n_nodes);
  gemm_kernel<<<512, 256, 0, stream>>>(node_feat, h1, h2, norm, W, bias, rst, n_nodes);
  est_kernel<<<4096, 256, 0, stream>>>(rst, src, est, n_edges);
}